// Round 1
// baseline (933.959 us; speedup 1.0000x reference)
//
#include <hip/hip_runtime.h>
#include <math.h>

#define NP 1000000
#define P 4096
#define D 64
#define H 4
#define HD 16

#define CH 4        // dims per scatter chunk
#define NCHUNK 16   // 16 * 4 = 64 dims
#define NSLICE 16   // event slices per chunk

#define QB 64       // q rows per flash block
#define RPT 4       // q rows per thread
#define KQ 16       // k-split within block
#define KC 4        // k-split across blocks
#define TK 64       // staged k rows per tile
#define KSTR 20     // padded LDS row stride (floats), 16B aligned, 2-way bank alias (free)

__device__ __forceinline__ float fast_tanh(float x) {
    float e = __expf(2.0f * x);
    return 1.0f - 2.0f / (e + 1.0f);
}
__device__ __forceinline__ float softplus_f(float x) {
    return fmaxf(x, 0.0f) + log1pf(__expf(-fabsf(x)));
}

// ---------------- counts histogram (LDS-privatized) ----------------
__global__ void hist_kernel(const int* __restrict__ pairs, float* __restrict__ counts) {
    __shared__ float lc[P];
    for (int i = threadIdx.x; i < P; i += blockDim.x) lc[i] = 0.0f;
    __syncthreads();
    const int total = 2 * NP;
    for (int i = blockIdx.x * blockDim.x + threadIdx.x; i < total; i += gridDim.x * blockDim.x)
        atomicAdd(&lc[pairs[i]], 1.0f);
    __syncthreads();
    for (int i = threadIdx.x; i < P; i += blockDim.x) {
        float vv = lc[i];
        if (vv != 0.0f) atomicAdd(&counts[i], vv);
    }
}

// ---------------- fused embed + segment-sum scatter ----------------
__global__ void scatter_kernel(const float* __restrict__ times, const float* __restrict__ mom,
                               const float* __restrict__ pos, const int* __restrict__ pairs,
                               const float* __restrict__ Wenc, const float* __restrict__ benc,
                               float* __restrict__ updates) {
    __shared__ float acc[P * CH];   // 64 KB
    const int chunk = blockIdx.x & (NCHUNK - 1);
    const int slice = blockIdx.x >> 4;
    for (int i = threadIdx.x; i < P * CH; i += blockDim.x) acc[i] = 0.0f;
    __syncthreads();
    const int d0 = chunk * CH;
    float w0[CH], w1[CH], w2[CH], bb[CH];
#pragma unroll
    for (int j = 0; j < CH; ++j) {
        w0[j] = Wenc[0 * D + d0 + j];
        w1[j] = Wenc[1 * D + d0 + j];
        w2[j] = Wenc[2 * D + d0 + j];
        bb[j] = benc[d0 + j];
    }
    const int2* pr2 = (const int2*)pairs;
    for (int e = slice * 256 + threadIdx.x; e < NP; e += NSLICE * 256) {
        float ft = times[e], fm = mom[e], fp = pos[e];
        int2 pq = pr2[e];
#pragma unroll
        for (int j = 0; j < CH; ++j) {
            float vv = fast_tanh(fmaf(ft, w0[j], fmaf(fm, w1[j], fmaf(fp, w2[j], bb[j]))));
            atomicAdd(&acc[pq.x * CH + j], vv);
            atomicAdd(&acc[pq.y * CH + j], vv);
        }
    }
    __syncthreads();
    for (int i = threadIdx.x; i < P * CH; i += blockDim.x) {
        float vv = acc[i];
        if (vv != 0.0f) atomicAdd(&updates[(i >> 2) * D + d0 + (i & 3)], vv);
    }
}

// ---------------- x = pemb + updates / max(counts,1) ----------------
__global__ void finalize_kernel(const float* __restrict__ pemb, const float* __restrict__ updates,
                                const float* __restrict__ counts, float* __restrict__ x) {
    int i = blockIdx.x * blockDim.x + threadIdx.x;   // over P*D/4
    const float4* u4 = (const float4*)updates;
    const float4* p4 = (const float4*)pemb;
    float4* x4 = (float4*)x;
    int bin = i >> 4;
    float inv = 1.0f / fmaxf(counts[bin], 1.0f);
    float4 u = u4[i], pe = p4[i];
    float4 r;
    r.x = fmaf(u.x, inv, pe.x); r.y = fmaf(u.y, inv, pe.y);
    r.z = fmaf(u.z, inv, pe.z); r.w = fmaf(u.w, inv, pe.w);
    x4[i] = r;
}

// ---------------- QKV projections ----------------
__global__ void qkv_kernel(const float* __restrict__ x,
                           const float* __restrict__ Wq, const float* __restrict__ bq,
                           const float* __restrict__ Wk, const float* __restrict__ bk,
                           const float* __restrict__ Wv, const float* __restrict__ bv,
                           float* __restrict__ q, float* __restrict__ k, float* __restrict__ v) {
    __shared__ float xs[4][D];
    const int r0 = blockIdx.x * 4;
    const int tid = threadIdx.x;
    xs[tid >> 6][tid & 63] = x[r0 * D + tid];
    __syncthreads();
    const int row = tid >> 6, col = tid & 63;
    float aq = bq[col], ak = bk[col], av = bv[col];
    for (int d = 0; d < D; ++d) {
        float xv = xs[row][d];
        aq = fmaf(xv, Wq[d * D + col], aq);
        ak = fmaf(xv, Wk[d * D + col], ak);
        av = fmaf(xv, Wv[d * D + col], av);
    }
    const int h = col >> 4, hd = col & 15, gr = r0 + row;
    q[(h * P + gr) * HD + hd] = aq;
    k[(h * P + gr) * HD + hd] = ak;
    v[(h * P + gr) * HD + hd] = av;
}

// ---------------- flash attention (fp32), K-split partials ----------------
__global__ void __launch_bounds__(256) flash_kernel(
        const float* __restrict__ q, const float* __restrict__ k, const float* __restrict__ v,
        float* __restrict__ pm, float* __restrict__ pl, float* __restrict__ pout) {
    __shared__ float smem[3072];     // kt(64*20) + vt(64*20) = 2560; merge reuses 3*1024
    float* kt = smem;
    float* vt = smem + TK * KSTR;
    const int bid = blockIdx.x;
    const int h = bid & 3;
    const int qb = (bid >> 2) & 63;
    const int kc = bid >> 8;
    const int tid = threadIdx.x;
    const int qt = tid & 15;
    const int kq = tid >> 4;

    float qv[RPT][HD], accv[RPT][HD], m[RPT], l[RPT];
    const int row0 = qb * QB + qt * RPT;
#pragma unroll
    for (int rr = 0; rr < RPT; ++rr) {
        const float4* qp = (const float4*)(q + (h * P + row0 + rr) * HD);
#pragma unroll
        for (int c = 0; c < 4; ++c) {
            float4 t = qp[c];
            qv[rr][c * 4 + 0] = t.x * 0.25f; qv[rr][c * 4 + 1] = t.y * 0.25f;
            qv[rr][c * 4 + 2] = t.z * 0.25f; qv[rr][c * 4 + 3] = t.w * 0.25f;
        }
        m[rr] = -INFINITY; l[rr] = 0.0f;
#pragma unroll
        for (int d2 = 0; d2 < HD; ++d2) accv[rr][d2] = 0.0f;
    }

    const int kbase = kc * (P / KC);
    for (int t = 0; t < (P / KC) / TK; ++t) {
        const int k0 = kbase + t * TK;
        __syncthreads();    // protect smem from previous tile's readers
        {
            int rrow = tid >> 2, cc = tid & 3;
            float4 kv4 = ((const float4*)(k + (h * P + k0 + rrow) * HD))[cc];
            ((float4*)(kt + rrow * KSTR))[cc] = kv4;
            float4 vv4 = ((const float4*)(v + (h * P + k0 + rrow) * HD))[cc];
            ((float4*)(vt + rrow * KSTR))[cc] = vv4;
        }
        __syncthreads();
#pragma unroll
        for (int jj = 0; jj < TK / KQ; ++jj) {
            const int j = kq * (TK / KQ) + jj;
            float kr[16], vr[16];
            *(float4*)(kr + 0)  = ((const float4*)(kt + j * KSTR))[0];
            *(float4*)(kr + 4)  = ((const float4*)(kt + j * KSTR))[1];
            *(float4*)(kr + 8)  = ((const float4*)(kt + j * KSTR))[2];
            *(float4*)(kr + 12) = ((const float4*)(kt + j * KSTR))[3];
            *(float4*)(vr + 0)  = ((const float4*)(vt + j * KSTR))[0];
            *(float4*)(vr + 4)  = ((const float4*)(vt + j * KSTR))[1];
            *(float4*)(vr + 8)  = ((const float4*)(vt + j * KSTR))[2];
            *(float4*)(vr + 12) = ((const float4*)(vt + j * KSTR))[3];
#pragma unroll
            for (int rr = 0; rr < RPT; ++rr) {
                float s = 0.0f;
#pragma unroll
                for (int d2 = 0; d2 < HD; ++d2) s = fmaf(qv[rr][d2], kr[d2], s);
                if (s > m[rr]) {
                    float cf = __expf(m[rr] - s);
                    m[rr] = s; l[rr] *= cf;
#pragma unroll
                    for (int d2 = 0; d2 < HD; ++d2) accv[rr][d2] *= cf;
                }
                float pexp = __expf(s - m[rr]);
                l[rr] += pexp;
#pragma unroll
                for (int d2 = 0; d2 < HD; ++d2) accv[rr][d2] = fmaf(pexp, vr[d2], accv[rr][d2]);
            }
        }
    }

    // merge the 16 kq partials per row via LDS
    __syncthreads();
    float* sm = smem;          // 64*16
    float* sl = smem + 1024;   // 64*16
    float* sout = smem + 2048; // 64*16
    for (int i = tid; i < 1024; i += 256) sout[i] = 0.0f;
#pragma unroll
    for (int rr = 0; rr < RPT; ++rr) {
        int rl = qt * RPT + rr;
        sm[rl * 16 + kq] = m[rr];
        sl[rl * 16 + kq] = l[rr];
    }
    __syncthreads();
    float Mrow[RPT], Lrow[RPT];
#pragma unroll
    for (int rr = 0; rr < RPT; ++rr) {
        int rl = qt * RPT + rr;
        float M = -INFINITY;
        for (int j2 = 0; j2 < 16; ++j2) M = fmaxf(M, sm[rl * 16 + j2]);
        float L = 0.0f;
        for (int j2 = 0; j2 < 16; ++j2) L += sl[rl * 16 + j2] * __expf(sm[rl * 16 + j2] - M);
        Mrow[rr] = M; Lrow[rr] = L;
        float sc = __expf(m[rr] - M);
#pragma unroll
        for (int d2 = 0; d2 < HD; ++d2) atomicAdd(&sout[rl * 16 + d2], accv[rr][d2] * sc);
    }
    __syncthreads();
#pragma unroll
    for (int rr = 0; rr < RPT; ++rr) {
        int rl = qt * RPT + rr;
        int grow = h * P + qb * QB + rl;
        if (kq == 0) {
            pm[grow * KC + kc] = Mrow[rr];
            pl[grow * KC + kc] = Lrow[rr];
        }
        pout[(grow * KC + kc) * HD + kq] = sout[rl * 16 + kq];
    }
}

// ---------------- merge K-chunk partials -> ctx ----------------
__global__ void attn_merge_kernel(const float* __restrict__ pm, const float* __restrict__ pl,
                                  const float* __restrict__ pout, float* __restrict__ ctx) {
    int g = blockIdx.x * blockDim.x + threadIdx.x;   // 0 .. H*P-1
    int h = g >> 12, row = g & 4095;
    float M = -INFINITY;
#pragma unroll
    for (int c = 0; c < KC; ++c) M = fmaxf(M, pm[g * KC + c]);
    float w[KC]; float L = 0.0f;
#pragma unroll
    for (int c = 0; c < KC; ++c) { w[c] = __expf(pm[g * KC + c] - M); L += pl[g * KC + c] * w[c]; }
    float inv = 1.0f / L;
#pragma unroll
    for (int d = 0; d < HD; ++d) {
        float s = 0.0f;
#pragma unroll
        for (int c = 0; c < KC; ++c) s = fmaf(pout[(g * KC + c) * HD + d], w[c], s);
        ctx[row * D + h * HD + d] = s * inv;
    }
}

// ---------------- output projection + MLP heads ----------------
__global__ void heads_kernel(const float* __restrict__ ctx,
                             const float* __restrict__ Wo, const float* __restrict__ bo,
                             const float* __restrict__ Wm1, const float* __restrict__ bm1,
                             const float* __restrict__ Wm2, const float* __restrict__ bm2,
                             const float* __restrict__ Wd1, const float* __restrict__ bd1,
                             const float* __restrict__ Wd2, const float* __restrict__ bd2,
                             float* __restrict__ out) {
    __shared__ float cs[4][D];
    __shared__ float x2[4][D];
    __shared__ float hid[4][D];
    const int r0 = blockIdx.x * 4;
    const int tid = threadIdx.x;
    cs[tid >> 6][tid & 63] = ctx[r0 * D + tid];
    __syncthreads();
    const int row = tid >> 6, col = tid & 63;
    float a = bo[col];
    for (int d = 0; d < D; ++d) a = fmaf(cs[row][d], Wo[d * D + col], a);
    x2[row][col] = a;
    __syncthreads();
    const int hc = col & 31;
    const float* W1 = (col < 32) ? Wm1 : Wd1;
    float hsum = (col < 32) ? bm1[hc] : bd1[hc];
    for (int d = 0; d < D; ++d) hsum = fmaf(x2[row][d], W1[d * 32 + hc], hsum);
    hsum = fmaxf(hsum, 0.0f);
    float w2 = (col < 32) ? Wm2[hc] : Wd2[hc];
    hid[row][col] = hsum * w2;
    __syncthreads();
    if (tid < 8) {
        int rr = tid >> 1, which = tid & 1;   // 0 = mass, 1 = diameter
        float s = which ? bd2[0] : bm2[0];
        for (int j2 = 0; j2 < 32; ++j2) s += hid[rr][which * 32 + j2];
        out[which * P + r0 + rr] = softplus_f(s);
    }
}

extern "C" void kernel_launch(void* const* d_in, const int* in_sizes, int n_in,
                              void* d_out, int out_size, void* d_ws, size_t ws_size,
                              hipStream_t stream) {
    const float* times = (const float*)d_in[0];
    const float* mom   = (const float*)d_in[1];
    const float* pos   = (const float*)d_in[2];
    const int*   pairs = (const int*)d_in[3];
    const float* Wenc  = (const float*)d_in[4];
    const float* benc  = (const float*)d_in[5];
    const float* pemb  = (const float*)d_in[6];
    const float* Wq = (const float*)d_in[7];   const float* bq = (const float*)d_in[8];
    const float* Wk = (const float*)d_in[9];   const float* bk = (const float*)d_in[10];
    const float* Wv = (const float*)d_in[11];  const float* bv = (const float*)d_in[12];
    const float* Wo = (const float*)d_in[13];  const float* bo = (const float*)d_in[14];
    const float* Wm1 = (const float*)d_in[15]; const float* bm1 = (const float*)d_in[16];
    const float* Wm2 = (const float*)d_in[17]; const float* bm2 = (const float*)d_in[18];
    const float* Wd1 = (const float*)d_in[19]; const float* bd1 = (const float*)d_in[20];
    const float* Wd2 = (const float*)d_in[21]; const float* bd2 = (const float*)d_in[22];

    float* ws      = (float*)d_ws;
    float* counts  = ws;                    // 4096
    float* updates = counts + P;            // 262144
    float* x       = updates + P * D;       // 262144
    float* q       = x + P * D;             // 262144
    float* k       = q + P * D;             // 262144
    float* v       = k + P * D;             // 262144
    float* pm      = v + P * D;             // 65536
    float* pl      = pm + H * P * KC;       // 65536
    float* pout    = pl + H * P * KC;       // 1048576
    float* ctx     = pout + H * P * KC * HD;// 262144
    float* out     = (float*)d_out;

    hipMemsetAsync(ws, 0, (size_t)(P + P * D) * sizeof(float), stream);
    hist_kernel<<<128, 256, 0, stream>>>(pairs, counts);
    scatter_kernel<<<NCHUNK * NSLICE, 256, 0, stream>>>(times, mom, pos, pairs, Wenc, benc, updates);
    finalize_kernel<<<(P * D / 4) / 256, 256, 0, stream>>>(pemb, updates, counts, x);
    qkv_kernel<<<P / 4, 256, 0, stream>>>(x, Wq, bq, Wk, bk, Wv, bv, q, k, v);
    flash_kernel<<<H * (P / QB) * KC, 256, 0, stream>>>(q, k, v, pm, pl, pout);
    attn_merge_kernel<<<(H * P) / 256, 256, 0, stream>>>(pm, pl, pout, ctx);
    heads_kernel<<<P / 4, 256, 0, stream>>>(ctx, Wo, bo, Wm1, bm1, Wm2, bm2, Wd1, bd1, Wd2, bd2, out);
}